// Round 7
// baseline (2724.052 us; speedup 1.0000x reference)
//
#include <hip/hip_runtime.h>
#include <hip/hip_bf16.h>
#include <math.h>

#define BB 16
#define TT 4096
#define HH 1024
#define SS 16
#define PP 6
#define NHH 8
#define DHH 128
#define NLL 2

typedef __hip_bfloat16 bf16;
typedef __attribute__((ext_vector_type(8))) short s8v;
typedef __attribute__((ext_vector_type(4))) float f32x4;
#define MFMA_B16(a,b,c) __builtin_amdgcn_mfma_f32_16x16x32_bf16((a),(b),(c),0,0,0)

__device__ __forceinline__ float b2f(bf16 x){ return __bfloat162float(x); }
__device__ __forceinline__ float us2f(unsigned short u){ return __uint_as_float(((unsigned)u) << 16); }
__device__ __forceinline__ int is_bf(const unsigned* lng){ return lng[0]==0x3F800000u ? 0 : 1; }
__device__ __forceinline__ float geluf(float v){ return 0.5f*v*(1.0f+erff(v*0.70710678118654752f)); }

// hi/lo bf16 split: x = hi + lo, representation error ~2^-16 relative
__device__ __forceinline__ void split_bf(float x, ushort& h, ushort& l){
    unsigned xb = __float_as_uint(x);
    unsigned hh = (xb + 0x7FFFu + ((xb>>16)&1u)) >> 16;
    float hf = __uint_as_float(hh<<16);
    float r = x - hf;
    unsigned rb = __float_as_uint(r);
    unsigned ll = (rb + 0x7FFFu + ((rb>>16)&1u)) >> 16;
    h=(ushort)hh; l=(ushort)ll;
}
template<int ISBF>
__device__ __forceinline__ float ldw(const void* p, size_t i){
    if (ISBF) return b2f(((const bf16*)p)[i]);
    else      return ((const float*)p)[i];
}

// ---------- segment mean pool (length reduce + scal zero folded in) ----------
__global__ __launch_bounds__(1024) void k_segpool(const void* __restrict__ tok,
        const int* __restrict__ mask, float* __restrict__ seg,
        ushort* __restrict__ sh, ushort* __restrict__ sl,
        float* __restrict__ scal, const unsigned* __restrict__ lng){
    __shared__ float sm[8*1024];
    int s = blockIdx.x, b = blockIdx.y, tid = threadIdx.x;
    if (s==0 && b==0 && tid==0){ scal[0]=0.f; scal[1]=0.f; scal[2]=0.f; scal[3]=0.f; }
    int* smi = (int*)sm;
    int a0i = 0;
    #pragma unroll
    for (int u=0;u<4;++u) a0i += mask[b*TT + tid + u*1024];
    smi[tid]=a0i; __syncthreads();
    for (int w=512;w>0;w>>=1){ if (tid<w) smi[tid]+=smi[tid+w]; __syncthreads(); }
    int len = smi[0];
    __syncthreads();
    int lo=(s*len)/SS, hi=((s+1)*len)/SS;
    float inv = 1.0f/(float)(hi-lo);
    if (is_bf(lng)){
        int ro = tid >> 7;
        int c8 = (tid & 127) << 3;
        float a[8];
        #pragma unroll
        for (int i=0;i<8;++i) a[i]=0.f;
        const unsigned short* t = (const unsigned short*)tok;
        for (int tt = lo + ro; tt < hi; tt += 8){
            uint4 u = *(const uint4*)(t + ((size_t)(b*TT + tt))*HH + c8);
            a[0]+=us2f((unsigned short)(u.x&0xffff)); a[1]+=us2f((unsigned short)(u.x>>16));
            a[2]+=us2f((unsigned short)(u.y&0xffff)); a[3]+=us2f((unsigned short)(u.y>>16));
            a[4]+=us2f((unsigned short)(u.z&0xffff)); a[5]+=us2f((unsigned short)(u.z>>16));
            a[6]+=us2f((unsigned short)(u.w&0xffff)); a[7]+=us2f((unsigned short)(u.w>>16));
        }
        #pragma unroll
        for (int i=0;i<8;++i) sm[ro*1024 + c8 + i] = a[i];
        __syncthreads();
        if (ro == 0){
            #pragma unroll
            for (int r=1;r<8;++r)
                #pragma unroll
                for (int i=0;i<8;++i) a[i] += sm[r*1024 + c8 + i];
            size_t base = ((size_t)(b*SS + s))*HH + c8;
            #pragma unroll
            for (int i=0;i<8;++i){
                float v = a[i]*inv;
                seg[base+i] = v;
                ushort h_,l_; split_bf(v,h_,l_);
                sh[base+i]=h_; sl[base+i]=l_;
            }
        }
    } else {
        int ro = tid >> 8;
        int c4 = (tid & 255) << 2;
        float a[4] = {0.f,0.f,0.f,0.f};
        const float* t = (const float*)tok;
        for (int tt = lo + ro; tt < hi; tt += 4){
            float4 u = *(const float4*)(t + ((size_t)(b*TT + tt))*HH + c4);
            a[0]+=u.x; a[1]+=u.y; a[2]+=u.z; a[3]+=u.w;
        }
        #pragma unroll
        for (int i=0;i<4;++i) sm[ro*1024 + c4 + i] = a[i];
        __syncthreads();
        if (ro == 0){
            #pragma unroll
            for (int r=1;r<4;++r)
                #pragma unroll
                for (int i=0;i<4;++i) a[i] += sm[r*1024 + c4 + i];
            size_t base = ((size_t)(b*SS + s))*HH + c4;
            #pragma unroll
            for (int i=0;i<4;++i) seg[base+i] = a[i]*inv;
        }
    }
}

// ---------- single-pass tiled GEMM: Y = act(X @ W[offW]^T + bias) (+R), 64x64 tile ----------
// bf16: MFMA hi/lo-split A (RAWA=1: A is raw input, exactly-bf16 => single MFMA).
// fp32: LDS 64x64 tile fallback.
template<int ACT,int RES,int SHAD,int RAWA>
__global__ __launch_bounds__(256) void k_gemm_t(
        const float* __restrict__ Xf, const ushort* __restrict__ Ah, const ushort* __restrict__ Al,
        const void* __restrict__ W, const void* __restrict__ bias, const float* __restrict__ Rres,
        float* __restrict__ Y, ushort* __restrict__ Yh, ushort* __restrict__ Yl,
        int N, int K, int M, size_t offW, int offB, const unsigned* __restrict__ lng){
    __shared__ float As[16][68], Bs[16][68];
    const int tid = threadIdx.x;
    const int c0 = blockIdx.x*64;
    if (is_bf(lng)){
        const int l=tid&63, wv=tid>>6, lr=l&15, lk=(l>>4)<<3;
        const int r0 = blockIdx.y*64 + wv*16;
        int ar = r0 + lr; if (ar > N-1) ar = N-1;
        const ushort* pah = Ah + (size_t)ar*K + lk;
        const ushort* pal = nullptr;
        if (!RAWA) pal = Al + (size_t)ar*K + lk;
        const ushort* pw = (const ushort*)W + offW + (size_t)(c0+lr)*K + lk;
        const size_t w16 = (size_t)16*K;
        f32x4 a0={0.f,0.f,0.f,0.f}, a1={0.f,0.f,0.f,0.f};
        f32x4 a2={0.f,0.f,0.f,0.f}, a3={0.f,0.f,0.f,0.f};
        for (int k=0;k<K;k+=32){
            s8v ah = *(const s8v*)pah;
            s8v b0 = *(const s8v*)pw;
            s8v b1 = *(const s8v*)(pw + w16);
            s8v b2 = *(const s8v*)(pw + 2*w16);
            s8v b3 = *(const s8v*)(pw + 3*w16);
            a0=MFMA_B16(ah,b0,a0); a1=MFMA_B16(ah,b1,a1);
            a2=MFMA_B16(ah,b2,a2); a3=MFMA_B16(ah,b3,a3);
            if (!RAWA){
                s8v al_ = *(const s8v*)pal;
                a0=MFMA_B16(al_,b0,a0); a1=MFMA_B16(al_,b1,a1);
                a2=MFMA_B16(al_,b2,a2); a3=MFMA_B16(al_,b3,a3);
                pal += 32;
            }
            pah += 32; pw += 32;
        }
        const int rb = r0 + ((l>>4)<<2);
        #pragma unroll
        for (int rg=0;rg<4;++rg){
            int r = rb+rg;
            if (r < N){
                float vv[4] = {a0[rg],a1[rg],a2[rg],a3[rg]};
                #pragma unroll
                for (int j=0;j<4;++j){
                    int col = c0 + j*16 + lr;
                    float v = vv[j] + ldw<1>(bias,(size_t)(offB+col));
                    if (ACT) v = geluf(v);
                    if (RES) v += Rres[(size_t)r*M+col];
                    Y[(size_t)r*M+col] = v;
                    if (SHAD){ ushort h_,l_; split_bf(v,h_,l_);
                        Yh[(size_t)r*M+col]=h_; Yl[(size_t)r*M+col]=l_; }
                }
            }
        }
    } else {
        const int r0 = blockIdx.y*64;
        const int tx = tid&15, ty = tid>>4, sr = tid>>2, sk = (tid&3)<<2;
        float c4[4][4] = {{0.f,0.f,0.f,0.f},{0.f,0.f,0.f,0.f},{0.f,0.f,0.f,0.f},{0.f,0.f,0.f,0.f}};
        const float* Xs = RAWA ? Xf : Xf;   // same pointer semantics
        for (int k0=0;k0<K;k0+=16){
            float4 av = make_float4(0.f,0.f,0.f,0.f);
            if (r0+sr < N) av = *(const float4*)(Xs + (size_t)(r0+sr)*K + k0 + sk);
            float4 bv = *(const float4*)((const float*)W + offW + (size_t)(c0+sr)*K + k0 + sk);
            As[sk+0][sr]=av.x; As[sk+1][sr]=av.y; As[sk+2][sr]=av.z; As[sk+3][sr]=av.w;
            Bs[sk+0][sr]=bv.x; Bs[sk+1][sr]=bv.y; Bs[sk+2][sr]=bv.z; Bs[sk+3][sr]=bv.w;
            __syncthreads();
            #pragma unroll
            for (int kk=0;kk<16;++kk){
                float4 a = *(const float4*)&As[kk][ty<<2];
                float4 b = *(const float4*)&Bs[kk][tx<<2];
                c4[0][0]+=a.x*b.x; c4[0][1]+=a.x*b.y; c4[0][2]+=a.x*b.z; c4[0][3]+=a.x*b.w;
                c4[1][0]+=a.y*b.x; c4[1][1]+=a.y*b.y; c4[1][2]+=a.y*b.z; c4[1][3]+=a.y*b.w;
                c4[2][0]+=a.z*b.x; c4[2][1]+=a.z*b.y; c4[2][2]+=a.z*b.z; c4[2][3]+=a.z*b.w;
                c4[3][0]+=a.w*b.x; c4[3][1]+=a.w*b.y; c4[3][2]+=a.w*b.z; c4[3][3]+=a.w*b.w;
            }
            __syncthreads();
        }
        #pragma unroll
        for (int i=0;i<4;++i){
            int r = r0 + (ty<<2) + i;
            if (r < N){
                #pragma unroll
                for (int j=0;j<4;++j){
                    int col = c0 + (tx<<2) + j;
                    float v = c4[i][j] + ((const float*)bias)[offB+col];
                    if (ACT) v = geluf(v);
                    if (RES) v += Rres[(size_t)r*M+col];
                    Y[(size_t)r*M+col] = v;
                }
            }
        }
    }
}

// ---------- full-row GEMM (M=K=1024) + bias (+res) (+Y preLN) + LayerNorm -> Z(+shadows) ----------
template<int RES,int HASY>
__global__ __launch_bounds__(512) void k_rowln(
        const float* __restrict__ Xf, const ushort* __restrict__ Ah, const ushort* __restrict__ Al,
        const void* __restrict__ W, const void* __restrict__ bias, const float* __restrict__ Rres,
        float* __restrict__ Y, float* __restrict__ Z, ushort* __restrict__ Zh, ushort* __restrict__ Zl,
        const void* __restrict__ g, const void* __restrict__ bta,
        size_t offW, int offB, int lnoff, const unsigned* __restrict__ lng){
    __shared__ float smx[8256+320];
    float* As  = smx;
    float* smS = smx + 8256;   // [8][16]
    float* smQ = smS + 128;    // [8][16]
    float* smM = smQ + 128;    // [16]
    float* smR = smM + 16;     // [16]
    const int tid = threadIdx.x;
    const int r0 = blockIdx.x*16;
    if (is_bf(lng)){
        const int w=tid>>6, l=tid&63, lr=l&15, lk=(l>>4)<<3, g4=l>>4;
        const ushort* pah = Ah + (size_t)(r0+lr)*HH + lk;
        const ushort* pal = Al + (size_t)(r0+lr)*HH + lk;
        const int cbase = w*128;
        const ushort* wp = (const ushort*)W + offW + (size_t)(cbase+lr)*HH + lk;
        const size_t w16 = (size_t)16*HH;
        f32x4 acc[8];
        #pragma unroll
        for (int s=0;s<8;++s) acc[s] = (f32x4){0.f,0.f,0.f,0.f};
        for (int k=0;k<HH;k+=32){
            s8v ah = *(const s8v*)pah;
            s8v al_ = *(const s8v*)pal;
            #pragma unroll
            for (int s=0;s<8;++s){
                s8v bv = *(const s8v*)(wp + (size_t)s*w16);
                acc[s]=MFMA_B16(ah,bv,acc[s]);
                acc[s]=MFMA_B16(al_,bv,acc[s]);
            }
            pah+=32; pal+=32; wp+=32;
        }
        float ps[4]={0.f,0.f,0.f,0.f}, pq[4]={0.f,0.f,0.f,0.f};
        #pragma unroll
        for (int s=0;s<8;++s){
            int col = cbase + s*16 + lr;
            float bv = ldw<1>(bias,(size_t)(offB+col));
            #pragma unroll
            for (int rg=0;rg<4;++rg){
                int r = r0 + g4*4 + rg;
                float v = acc[s][rg] + bv;
                if (RES)  v += Rres[(size_t)r*HH+col];
                if (HASY) Y[(size_t)r*HH+col] = v;
                acc[s][rg] = v;
                ps[rg]+=v; pq[rg]+=v*v;
            }
        }
        #pragma unroll
        for (int m=1;m<16;m<<=1){
            #pragma unroll
            for (int rg=0;rg<4;++rg){
                ps[rg]+=__shfl_xor(ps[rg],m);
                pq[rg]+=__shfl_xor(pq[rg],m);
            }
        }
        if (lr==0){
            #pragma unroll
            for (int rg=0;rg<4;++rg){ smS[w*16+g4*4+rg]=ps[rg]; smQ[w*16+g4*4+rg]=pq[rg]; }
        }
        __syncthreads();
        if (tid<16){
            float S=0.f,Q=0.f;
            #pragma unroll
            for (int ww=0;ww<8;++ww){ S+=smS[ww*16+tid]; Q+=smQ[ww*16+tid]; }
            float mean=S*(1.0f/HH);
            float var=fmaxf(Q*(1.0f/HH)-mean*mean,0.f);
            smM[tid]=mean; smR[tid]=rsqrtf(var+1e-5f);
        }
        __syncthreads();
        #pragma unroll
        for (int s=0;s<8;++s){
            int col = cbase + s*16 + lr;
            float gg = ldw<1>(g,(size_t)(lnoff+col));
            float bb = ldw<1>(bta,(size_t)(lnoff+col));
            #pragma unroll
            for (int rg=0;rg<4;++rg){
                int r = r0 + g4*4 + rg;
                float zv = (acc[s][rg]-smM[g4*4+rg])*smR[g4*4+rg]*gg+bb;
                Z[(size_t)r*HH+col]=zv;
                ushort h_,l_; split_bf(zv,h_,l_);
                Zh[(size_t)r*HH+col]=h_; Zl[(size_t)r*HH+col]=l_;
            }
        }
    } else {
        // fp32 fallback: thread owns cols {tid, tid+512}, all 16 rows
        float acc0[16], acc1[16];
        #pragma unroll
        for (int r=0;r<16;++r){ acc0[r]=0.f; acc1[r]=0.f; }
        const float* Wf = (const float*)W;
        for (int ko=0;ko<HH;ko+=512){
            for (int i=tid;i<16*512;i+=512){ int rr=i>>9, cc=i&511; As[rr*516+cc]=Xf[(size_t)(r0+rr)*HH+ko+cc]; }
            __syncthreads();
            const float* wp0 = Wf + offW + (size_t)tid*HH + ko;
            const float* wp1 = Wf + offW + (size_t)(tid+512)*HH + ko;
            for (int k=0;k<512;++k){
                float wa=wp0[k], wb=wp1[k];
                #pragma unroll
                for (int r=0;r<16;++r){ float av=As[r*516+k]; acc0[r]+=av*wa; acc1[r]+=av*wb; }
            }
            __syncthreads();
        }
        const float* bf_ = (const float*)bias;
        float b0=bf_[offB+tid], b1v=bf_[offB+tid+512];
        float s16[16], q16[16];
        #pragma unroll
        for (int r=0;r<16;++r){
            float v0=acc0[r]+b0, v1=acc1[r]+b1v;
            if (RES){ v0+=Rres[(size_t)(r0+r)*HH+tid]; v1+=Rres[(size_t)(r0+r)*HH+tid+512]; }
            if (HASY){ Y[(size_t)(r0+r)*HH+tid]=v0; Y[(size_t)(r0+r)*HH+tid+512]=v1; }
            acc0[r]=v0; acc1[r]=v1;
            s16[r]=v0+v1; q16[r]=v0*v0+v1*v1;
        }
        #pragma unroll
        for (int m=1;m<64;m<<=1){
            #pragma unroll
            for (int r=0;r<16;++r){ s16[r]+=__shfl_xor(s16[r],m); q16[r]+=__shfl_xor(q16[r],m); }
        }
        int w=tid>>6, l=tid&63;
        if (l==0){
            #pragma unroll
            for (int r=0;r<16;++r){ smS[w*16+r]=s16[r]; smQ[w*16+r]=q16[r]; }
        }
        __syncthreads();
        if (tid<16){
            float S=0.f,Q=0.f;
            #pragma unroll
            for (int ww=0;ww<8;++ww){ S+=smS[ww*16+tid]; Q+=smQ[ww*16+tid]; }
            float mean=S*(1.0f/HH);
            float var=fmaxf(Q*(1.0f/HH)-mean*mean,0.f);
            smM[tid]=mean; smR[tid]=rsqrtf(var+1e-5f);
        }
        __syncthreads();
        const float* gf=(const float*)g; const float* btf=(const float*)bta;
        float g0=gf[lnoff+tid], g1=gf[lnoff+tid+512];
        float t0=btf[lnoff+tid], t1v=btf[lnoff+tid+512];
        #pragma unroll
        for (int r=0;r<16;++r){
            Z[(size_t)(r0+r)*HH+tid]     =(acc0[r]-smM[r])*smR[r]*g0+t0;
            Z[(size_t)(r0+r)*HH+tid+512] =(acc1[r]-smM[r])*smR[r]*g1+t1v;
        }
    }
}

// ---------- fused salience: GEMM+GELU -> logits -> softmax+entropy -> wseg ----------
__global__ __launch_bounds__(512) void k_sal(
        const float* __restrict__ segF, const ushort* __restrict__ segH, const ushort* __restrict__ segL,
        const void* __restrict__ w1, const void* __restrict__ b1,
        const void* __restrict__ w2, const void* __restrict__ b2v,
        float* __restrict__ sal, float* __restrict__ t2, ushort* __restrict__ t2h, ushort* __restrict__ t2l,
        float* __restrict__ scal, const unsigned* __restrict__ lng){
    __shared__ float smx[8256+320];
    float* As  = smx;
    float* smS = smx + 8256;   // [8][16]
    float* lgv = smS + 128;    // [16]
    float* salv= lgv + 16;     // [16]
    const int tid = threadIdx.x, b = blockIdx.x;
    const int r0 = b*16;
    const int bfm = is_bf(lng);
    if (bfm){
        const int w=tid>>6, l=tid&63, lr=l&15, lk=(l>>4)<<3, g4=l>>4;
        const ushort* pah = segH + (size_t)(r0+lr)*HH + lk;
        const ushort* pal = segL + (size_t)(r0+lr)*HH + lk;
        const int cbase = w*128;
        const ushort* wp = (const ushort*)w1 + (size_t)(cbase+lr)*HH + lk;
        const size_t w16 = (size_t)16*HH;
        f32x4 acc[8];
        #pragma unroll
        for (int s=0;s<8;++s) acc[s] = (f32x4){0.f,0.f,0.f,0.f};
        for (int k=0;k<HH;k+=32){
            s8v ah = *(const s8v*)pah;
            s8v al_ = *(const s8v*)pal;
            #pragma unroll
            for (int s=0;s<8;++s){
                s8v bv = *(const s8v*)(wp + (size_t)s*w16);
                acc[s]=MFMA_B16(ah,bv,acc[s]);
                acc[s]=MFMA_B16(al_,bv,acc[s]);
            }
            pah+=32; pal+=32; wp+=32;
        }
        float ls[4]={0.f,0.f,0.f,0.f};
        #pragma unroll
        for (int s=0;s<8;++s){
            int col = cbase + s*16 + lr;
            float bb = ldw<1>(b1,(size_t)col);
            float w2v = ldw<1>(w2,(size_t)col);
            #pragma unroll
            for (int rg=0;rg<4;++rg) ls[rg] += geluf(acc[s][rg]+bb)*w2v;
        }
        #pragma unroll
        for (int m=1;m<16;m<<=1){
            #pragma unroll
            for (int rg=0;rg<4;++rg) ls[rg]+=__shfl_xor(ls[rg],m);
        }
        if (lr==0){
            #pragma unroll
            for (int rg=0;rg<4;++rg) smS[w*16+g4*4+rg]=ls[rg];
        }
        __syncthreads();
        if (tid<16){
            float S=0.f;
            #pragma unroll
            for (int ww=0;ww<8;++ww) S+=smS[ww*16+tid];
            lgv[tid]=S+ldw<1>(b2v,0);
        }
        __syncthreads();
    } else {
        float acc0[16], acc1[16];
        #pragma unroll
        for (int r=0;r<16;++r){ acc0[r]=0.f; acc1[r]=0.f; }
        const float* w1f=(const float*)w1;
        for (int ko=0;ko<HH;ko+=512){
            for (int i=tid;i<16*512;i+=512){ int rr=i>>9, cc=i&511; As[rr*516+cc]=segF[(size_t)(r0+rr)*HH+ko+cc]; }
            __syncthreads();
            const float* wp0 = w1f + (size_t)tid*HH + ko;
            const float* wp1 = w1f + (size_t)(tid+512)*HH + ko;
            for (int k=0;k<512;++k){
                float wa=wp0[k], wb=wp1[k];
                #pragma unroll
                for (int r=0;r<16;++r){ float av=As[r*516+k]; acc0[r]+=av*wa; acc1[r]+=av*wb; }
            }
            __syncthreads();
        }
        const float* b1f=(const float*)b1; const float* w2f=(const float*)w2;
        float ba=b1f[tid], bb=b1f[tid+512];
        float wa2=w2f[tid], wb2=w2f[tid+512];
        float ls[16];
        #pragma unroll
        for (int r=0;r<16;++r)
            ls[r]=geluf(acc0[r]+ba)*wa2 + geluf(acc1[r]+bb)*wb2;
        #pragma unroll
        for (int m=1;m<64;m<<=1){
            #pragma unroll
            for (int r=0;r<16;++r) ls[r]+=__shfl_xor(ls[r],m);
        }
        int w=tid>>6, l=tid&63;
        if (l==0){
            #pragma unroll
            for (int r=0;r<16;++r) smS[w*16+r]=ls[r];
        }
        __syncthreads();
        if (tid<16){
            float S=0.f;
            #pragma unroll
            for (int ww=0;ww<8;++ww) S+=smS[ww*16+tid];
            lgv[tid]=S+((const float*)b2v)[0];
        }
        __syncthreads();
    }
    if (tid==0){
        float m=-1e30f;
        for (int s2=0;s2<SS;++s2) m=fmaxf(m,lgv[s2]);
        float ev[SS]; float ssum=0.f;
        for (int s2=0;s2<SS;++s2){ ev[s2]=expf(lgv[s2]-m); ssum+=ev[s2]; }
        float inv2=1.0f/ssum, ent=0.f;
        for (int s2=0;s2<SS;++s2){
            float p=ev[s2]*inv2;
            salv[s2]=p; sal[b*SS+s2]=p;
            ent-=p*logf(p+1e-8f);
        }
        atomicAdd(&scal[0], ent);
    }
    __syncthreads();
    for (int i=tid;i<SS*HH;i+=512){
        int rr=i>>10;
        float v = segF[(size_t)r0*HH + i] * salv[rr];
        size_t oi=(size_t)r0*HH + i;
        t2[oi]=v;
        if (bfm){ ushort h_,l_; split_bf(v,h_,l_); t2h[oi]=h_; t2l[oi]=l_; }
    }
}

// ---------- MHA core (fp32 math; optional bf16 hi/lo shadow of O) ----------
__global__ __launch_bounds__(256) void k_attn(const float* __restrict__ Qb, const float* __restrict__ Kb,
                       const float* __restrict__ Vb, float* __restrict__ O,
                       ushort* __restrict__ Oh, ushort* __restrict__ Ol,
                       int nq, int nk, int sQ, int sKV, int qShared,
                       const unsigned* __restrict__ lng){
    __shared__ float Qs[16][132], Ks[16][132], Vs[16][132];
    __shared__ float sc[16][17];
    int b = blockIdx.x / NHH, h = blockIdx.x % NHH;
    int tid = threadIdx.x;
    int bfm = is_bf(lng);
    for (int idx=tid; idx<nq*32; idx+=256){
        int i = idx>>5, d4=(idx&31)<<2;
        int r = qShared ? i : (b*nq+i);
        *(float4*)&Qs[i][d4] = *(const float4*)&Qb[(size_t)r*sQ + h*DHH + d4];
    }
    for (int idx=tid; idx<nk*32; idx+=256){
        int j=idx>>5, d4=(idx&31)<<2;
        *(float4*)&Ks[j][d4] = *(const float4*)&Kb[(size_t)(b*nk+j)*sKV + h*DHH + d4];
        *(float4*)&Vs[j][d4] = *(const float4*)&Vb[(size_t)(b*nk+j)*sKV + h*DHH + d4];
    }
    __syncthreads();
    const float scale = 0.0883883476483184406f;
    for (int idx=tid; idx<nq*nk; idx+=256){
        int i=idx/nk, j=idx-i*nk;
        const float4* qp=(const float4*)&Qs[i][0];
        const float4* kp=(const float4*)&Ks[j][0];
        float ax=0.f,ay=0.f,az=0.f,aw=0.f;
        #pragma unroll
        for (int k4=0;k4<32;++k4){
            float4 a=qp[k4], c=kp[k4];
            ax+=a.x*c.x; ay+=a.y*c.y; az+=a.z*c.z; aw+=a.w*c.w;
        }
        sc[i][j]=(ax+ay+az+aw)*scale;
    }
    __syncthreads();
    if (tid<nq){
        float m=-1e30f;
        for (int j=0;j<nk;++j) m=fmaxf(m,sc[tid][j]);
        float ssum=0.f;
        for (int j=0;j<nk;++j){ float e=expf(sc[tid][j]-m); sc[tid][j]=e; ssum+=e; }
        float inv=1.0f/ssum;
        for (int j=0;j<nk;++j) sc[tid][j]*=inv;
    }
    __syncthreads();
    for (int idx=tid; idx<nq*32; idx+=256){
        int i=idx>>5, d4=(idx&31)<<2;
        float ox=0.f,oy=0.f,oz=0.f,ow=0.f;
        for (int j=0;j<nk;++j){
            float s=sc[i][j];
            float4 v=*(const float4*)&Vs[j][d4];
            ox+=s*v.x; oy+=s*v.y; oz+=s*v.z; ow+=s*v.w;
        }
        size_t oidx=(size_t)(b*nq+i)*HH + h*DHH + d4;
        *(float4*)&O[oidx]=make_float4(ox,oy,oz,ow);
        if (bfm){
            ushort4 hv,lv;
            split_bf(ox,hv.x,lv.x); split_bf(oy,hv.y,lv.y);
            split_bf(oz,hv.z,lv.z); split_bf(ow,hv.w,lv.w);
            *(ushort4*)&Oh[oidx]=hv; *(ushort4*)&Ol[oidx]=lv;
        }
    }
}

// ---------- plain LayerNorm (inter-layer) ----------
__global__ __launch_bounds__(256) void k_ln(const float* __restrict__ X, const void* __restrict__ g,
        const void* __restrict__ bta, float* __restrict__ Z,
        ushort* __restrict__ Zh, ushort* __restrict__ Zl, int off,
        const unsigned* __restrict__ lng){
    int row=blockIdx.x, tid=threadIdx.x;
    const float* x = X + (size_t)row*HH;
    float v[4]; float s=0.f, sq=0.f;
    #pragma unroll
    for (int u=0;u<4;++u){ v[u]=x[tid+u*256]; s+=v[u]; sq+=v[u]*v[u]; }
    __shared__ float r1[256], r2[256];
    r1[tid]=s; r2[tid]=sq; __syncthreads();
    for (int w=128;w>0;w>>=1){
        if (tid<w){ r1[tid]+=r1[tid+w]; r2[tid]+=r2[tid+w]; }
        __syncthreads();
    }
    float mean=r1[0]*(1.0f/HH);
    float var=fmaxf(r2[0]*(1.0f/HH)-mean*mean,0.f);
    float rstd=rsqrtf(var+1e-5f);
    int bfm = is_bf(lng);
    #pragma unroll
    for (int u=0;u<4;++u){
        int c=tid+u*256;
        float gv = bfm ? b2f(((const bf16*)g)[off+c])   : ((const float*)g)[off+c];
        float bv = bfm ? b2f(((const bf16*)bta)[off+c]) : ((const float*)bta)[off+c];
        float zv=(v[u]-mean)*rstd*gv+bv;
        Z[(size_t)row*HH+c]=zv;
        if (bfm){ ushort h_,l_; split_bf(zv,h_,l_);
            Zh[(size_t)row*HH+c]=h_; Zl[(size_t)row*HH+c]=l_; }
    }
}

// ---------- redundancy: per-batch block computes 21 dots + combines ----------
__global__ __launch_bounds__(256) void k_red(const float* __restrict__ plan, float* __restrict__ scal){
    __shared__ float Pl[PP][HH];
    __shared__ float red[256];
    __shared__ float dv[21];
    int b=blockIdx.x, tid=threadIdx.x;
    for (int i=tid;i<PP*HH;i+=256) Pl[i>>10][i&1023]=plan[(size_t)b*PP*HH+i];
    __syncthreads();
    const int PRa[21]={0,1,2,3,4,5, 0,0,0,0,0,1,1,1,1,2,2,2,3,3,4};
    const int QRa[21]={0,1,2,3,4,5, 1,2,3,4,5,2,3,4,5,3,4,5,4,5,5};
    for (int t=0;t<21;++t){
        float a=0.f;
        #pragma unroll
        for (int u=0;u<4;++u){ int c=tid+u*256; a+=Pl[PRa[t]][c]*Pl[QRa[t]][c]; }
        red[tid]=a; __syncthreads();
        for (int w=128;w>0;w>>=1){ if (tid<w) red[tid]+=red[tid+w]; __syncthreads(); }
        if (tid==0) dv[t]=red[0];
        __syncthreads();
    }
    if (tid==0){
        float n[PP];
        #pragma unroll
        for (int p=0;p<PP;++p) n[p]=fmaxf(sqrtf(dv[p]),1e-12f);
        float tot=0.f;
        for (int k=6;k<21;++k){
            float s=dv[k]/(n[PRa[k]]*n[QRa[k]]);
            tot+=2.0f*s*s;
        }
        atomicAdd(&scal[1], tot);
    }
}

// ---------- output assembly ----------
__global__ __launch_bounds__(256) void k_out(const float* __restrict__ plan, const float* __restrict__ sal,
                      const float* __restrict__ scal, void* __restrict__ outv,
                      const unsigned* __restrict__ lng){
    int i = blockIdx.x*256 + threadIdx.x;
    const int NPLAN = BB*PP*HH;
    const int NSAL  = BB*SS;
    float v;
    if (i < NPLAN) v = plan[i];
    else if (i < NPLAN+NSAL) v = sal[i-NPLAN];
    else if (i == NPLAN+NSAL) v = scal[0]*(1.0f/BB);
    else if (i == NPLAN+NSAL+1) v = scal[1]*(1.0f/(BB*PP*(PP-1)));
    else return;
    if (is_bf(lng)) ((bf16*)outv)[i]=__float2bfloat16(v);
    else            ((float*)outv)[i]=v;
}

extern "C" void kernel_launch(void* const* d_in, const int* in_sizes, int n_in,
                              void* d_out, int out_size, void* d_ws, size_t ws_size,
                              hipStream_t stream) {
    const void* tok      = d_in[0];
    const int*  mask     = (const int*)d_in[1];
    const void* sa_in_w  = d_in[2];
    const void* sa_in_b  = d_in[3];
    const void* sa_out_w = d_in[4];
    const void* sa_out_b = d_in[5];
    const void* ln_g     = d_in[6];
    const void* ln_b     = d_in[7];
    const void* sal_w1   = d_in[8];
    const void* sal_b1   = d_in[9];
    const void* sal_w2   = d_in[10];
    const void* sal_b2   = d_in[11];
    const void* plan_q   = d_in[12];
    const void* qa_in_w  = d_in[13];
    const void* qa_in_b  = d_in[14];
    const void* qa_out_w = d_in[15];
    const void* qa_out_b = d_in[16];
    const void* r_in_w   = d_in[17];
    const void* r_in_b   = d_in[18];
    const void* r_out_w  = d_in[19];
    const void* r_out_b  = d_in[20];
    const void* r_ln1_g  = d_in[21];
    const void* r_ln1_b  = d_in[22];
    const void* r_ln2_g  = d_in[23];
    const void* r_ln2_b  = d_in[24];
    const void* r_w1     = d_in[25];
    const void* r_b1     = d_in[26];
    const void* r_w2     = d_in[27];
    const void* r_b2     = d_in[28];
    const unsigned* lng  = (const unsigned*)ln_g;

    float* ws   = (float*)d_ws;
    float* seg  = ws;                      // 256x1024
    float* qkv  = seg  + BB*SS*HH;         // 256x3072 (also 256x2048 kv)
    float* t1   = qkv  + BB*SS*3*HH;       // 256x1024
    float* t2   = t1   + BB*SS*HH;         // 256x1024 (wseg)
    float* plan = t2   + BB*SS*HH;         // 96x1024
    float* ybuf = plan + BB*PP*HH;         // 96x1024
    float* qkv2 = ybuf + BB*PP*HH;         // 96x4096 (in-proj 96x3072 / ffn 96x4096)
    float* pbuf = qkv2 + BB*PP*4*HH;       // 96x1024
    float* qh   = pbuf + BB*PP*HH;         // 16x1024 (rows 0-5 valid)
    float* sal  = qh   + 16*HH;            // 256
    // bf16 hi/lo shadow planes
    ushort* segh = (ushort*)(sal + BB*SS);
    ushort* segl = segh + BB*SS*HH;
    ushort* t1h  = segl + BB*SS*HH;
    ushort* t1l  = t1h  + BB*SS*HH;
    ushort* t2h  = t1l  + BB*SS*HH;
    ushort* t2l  = t2h  + BB*SS*HH;
    ushort* pbh  = t2l  + BB*SS*HH;
    ushort* pbl  = pbh  + BB*PP*HH;
    ushort* ybh  = pbl  + BB*PP*HH;
    ushort* ybl  = ybh  + BB*PP*HH;
    ushort* ffh  = ybl  + BB*PP*HH;
    ushort* ffl  = ffh  + BB*PP*4*HH;
    float*  scal = (float*)(ffl + BB*PP*4*HH);  // 4

    k_segpool<<<dim3(SS,BB),1024,0,stream>>>(tok, mask, seg, segh, segl, scal, lng);

    // --- self-attention over segments ---
    k_gemm_t<0,0,0,0><<<dim3(48,4),256,0,stream>>>(seg, segh, segl, sa_in_w, sa_in_b, nullptr,
        qkv, nullptr, nullptr, BB*SS, HH, 3*HH, (size_t)0, 0, lng);
    k_attn<<<BB*NHH,256,0,stream>>>(qkv, qkv+HH, qkv+2*HH, t1, t1h, t1l, SS, SS, 3*HH, 3*HH, 0, lng);
    k_rowln<1,0><<<16,512,0,stream>>>(t1, t1h, t1l, sa_out_w, sa_out_b, seg,
        nullptr, seg, segh, segl, ln_g, ln_b, (size_t)0, 0, 0, lng);

    // --- salience (GEMM+GELU+logits+softmax+entropy+wseg fused) ---
    k_sal<<<BB,512,0,stream>>>(seg, segh, segl, sal_w1, sal_b1, sal_w2, sal_b2,
        sal, t2, t2h, t2l, scal, lng);

    // --- plan attention ---
    k_gemm_t<0,0,0,1><<<dim3(16,1),256,0,stream>>>((const float*)plan_q, (const ushort*)plan_q, nullptr,
        qa_in_w, qa_in_b, nullptr, qh, nullptr, nullptr, PP, HH, HH, (size_t)0, 0, lng);
    k_gemm_t<0,0,0,0><<<dim3(32,4),256,0,stream>>>(t2, t2h, t2l, qa_in_w, qa_in_b, nullptr,
        qkv, nullptr, nullptr, BB*SS, HH, 2*HH, (size_t)HH*HH, HH, lng);
    k_attn<<<BB*NHH,256,0,stream>>>(qh, qkv, qkv+HH, pbuf, pbh, pbl, PP, SS, HH, 2*HH, 1, lng);
    k_rowln<0,1><<<6,512,0,stream>>>(pbuf, pbh, pbl, qa_out_w, qa_out_b, nullptr,
        plan, ybuf, ybh, ybl, r_ln1_g, r_ln1_b, (size_t)0, 0, 0, lng);

    // --- NL transformer encoder layers ---
    for (int l=0;l<NLL;++l){
        k_gemm_t<0,0,0,0><<<dim3(48,2),256,0,stream>>>(ybuf, ybh, ybl, r_in_w, r_in_b, nullptr,
            qkv2, nullptr, nullptr, BB*PP, HH, 3*HH, (size_t)l*3*HH*HH, l*3*HH, lng);
        k_attn<<<BB*NHH,256,0,stream>>>(qkv2, qkv2+HH, qkv2+2*HH, pbuf, pbh, pbl, PP, PP, 3*HH, 3*HH, 0, lng);
        k_rowln<1,1><<<6,512,0,stream>>>(pbuf, pbh, pbl, r_out_w, r_out_b, plan,
            plan, ybuf, ybh, ybl, r_ln2_g, r_ln2_b, (size_t)l*HH*HH, l*HH, l*HH, lng);
        k_gemm_t<1,0,1,0><<<dim3(64,2),256,0,stream>>>(ybuf, ybh, ybl, r_w1, r_b1, nullptr,
            qkv2, ffh, ffl, BB*PP, HH, 4*HH, (size_t)l*4*HH*HH, l*4*HH, lng);
        k_gemm_t<0,1,0,0><<<dim3(16,2),256,0,stream>>>(qkv2, ffh, ffl, r_w2, r_b2, plan,
            plan, nullptr, nullptr, BB*PP, 4*HH, HH, (size_t)l*HH*4*HH, l*HH, lng);
        if (l < NLL-1)
            k_ln<<<BB*PP,256,0,stream>>>(plan, r_ln1_g, r_ln1_b, ybuf, ybh, ybl, (l+1)*HH, lng);
    }

    // --- scalars + output ---
    k_red<<<BB,256,0,stream>>>(plan, scal);
    k_out<<<(BB*PP*HH + BB*SS + 2 + 255)/256,256,0,stream>>>(plan, sal, scal, d_out, lng);
}